// Round 10
// baseline (515.145 us; speedup 1.0000x reference)
//
#include <hip/hip_runtime.h>

// ---------------- types / helpers ----------------
typedef __attribute__((ext_vector_type(8))) short bf16x8;   // 8 bf16 (4 VGPRs)
typedef __attribute__((ext_vector_type(4))) float f32x4;    // MFMA accum
typedef __attribute__((ext_vector_type(8))) unsigned short u16x8;

#define D_MODEL 2048
#define NH 16
#define HD 128
#define SKV 3072
#define QK_SCALE 0.08838834764831845f  // 128^-0.5
#define LOG2E 1.4426950408889634f
#define DEFER_THR 11.5413f             // 8 * log2(e)

__device__ __forceinline__ unsigned short f2bf(float f) {
  unsigned int u = __float_as_uint(f);
  u += 0x7fffu + ((u >> 16) & 1u);     // RNE, finite inputs only
  return (unsigned short)(u >> 16);
}
__device__ __forceinline__ float exp2hw(float x) {
  float r; asm("v_exp_f32 %0, %1" : "=v"(r) : "v"(x)); return r;
}
__device__ __forceinline__ unsigned int cvtpk(float lo, float hi) {
  unsigned int r; asm("v_cvt_pk_bf16_f32 %0, %1, %2" : "=v"(r) : "v"(lo), "v"(hi)); return r;
}

typedef __attribute__((address_space(1))) void as1_void;
typedef __attribute__((address_space(3))) void as3_void;
__device__ __forceinline__ void gload_lds16(const void* g, void* l) {
  __builtin_amdgcn_global_load_lds((as1_void*)g, (as3_void*)l, 16, 0, 0);
}

#define MFMA16(a, b, c) __builtin_amdgcn_mfma_f32_16x16x32_bf16((a), (b), (c), 0, 0, 0)

// ---------------- weight convert: all 4 weights in one dispatch ----------------
__global__ __launch_bounds__(256) void cvt_w_kernel(
    const float* __restrict__ s0, const float* __restrict__ s1,
    const float* __restrict__ s2, const float* __restrict__ s3,
    unsigned short* __restrict__ dstbase) {
  const int y = blockIdx.y;
  const float* src = (y == 0) ? s0 : (y == 1) ? s1 : (y == 2) ? s2 : s3;
  const float scale = (y == 0) ? (QK_SCALE * LOG2E) : 1.0f;   // fold softmax+log2e into Wq
  unsigned short* dst = dstbase + (size_t)y * 4194304;
  int i = blockIdx.x * 256 + threadIdx.x;
  const float4* s = (const float4*)src + (size_t)i * 2;
  float4 a = s[0], b = s[1];
  u16x8 r;
  r[0] = f2bf(a.x * scale); r[1] = f2bf(a.y * scale);
  r[2] = f2bf(a.z * scale); r[3] = f2bf(a.w * scale);
  r[4] = f2bf(b.x * scale); r[5] = f2bf(b.y * scale);
  r[6] = f2bf(b.z * scale); r[7] = f2bf(b.w * scale);
  *((u16x8*)dst + i) = r;
}

// ---------------- LayerNorm -> bf16 (with row remap for K concat) ----------------
__global__ __launch_bounds__(256) void ln_kernel(
    const float* __restrict__ x, const float* __restrict__ gw,
    const float* __restrict__ bw, unsigned short* __restrict__ out,
    int spb, int orpb, int obase) {
  const int row = blockIdx.x;
  const int t = threadIdx.x;
  const int b = row / spb, s = row - b * spb;
  const float* xr = x + (size_t)row * D_MODEL;
  unsigned short* orow = out + ((size_t)b * orpb + obase + s) * D_MODEL;

  float4 v0 = *(const float4*)(xr + t * 8);
  float4 v1 = *(const float4*)(xr + t * 8 + 4);
  float sum = v0.x + v0.y + v0.z + v0.w + v1.x + v1.y + v1.z + v1.w;
  float sq  = v0.x*v0.x + v0.y*v0.y + v0.z*v0.z + v0.w*v0.w
            + v1.x*v1.x + v1.y*v1.y + v1.z*v1.z + v1.w*v1.w;
#pragma unroll
  for (int o = 32; o > 0; o >>= 1) {
    sum += __shfl_down(sum, o);
    sq  += __shfl_down(sq, o);
  }
  __shared__ float red[8];
  const int wv = t >> 6, l = t & 63;
  if (l == 0) { red[wv] = sum; red[4 + wv] = sq; }
  __syncthreads();
  sum = red[0] + red[1] + red[2] + red[3];
  sq  = red[4] + red[5] + red[6] + red[7];
  const float mu = sum * (1.0f / 2048.0f);
  const float var = sq * (1.0f / 2048.0f) - mu * mu;
  const float rs = rsqrtf(var + 1e-5f);

  float4 g0 = *(const float4*)(gw + t * 8);
  float4 g1 = *(const float4*)(gw + t * 8 + 4);
  float4 b0 = *(const float4*)(bw + t * 8);
  float4 b1 = *(const float4*)(bw + t * 8 + 4);
  u16x8 r;
  r[0] = f2bf((v0.x - mu) * rs * g0.x + b0.x);
  r[1] = f2bf((v0.y - mu) * rs * g0.y + b0.y);
  r[2] = f2bf((v0.z - mu) * rs * g0.z + b0.z);
  r[3] = f2bf((v0.w - mu) * rs * g0.w + b0.w);
  r[4] = f2bf((v1.x - mu) * rs * g1.x + b1.x);
  r[5] = f2bf((v1.y - mu) * rs * g1.y + b1.y);
  r[6] = f2bf((v1.z - mu) * rs * g1.z + b1.z);
  r[7] = f2bf((v1.w - mu) * rs * g1.w + b1.w);
  *(u16x8*)(orow + t * 8) = r;
}

// ---------------- GEMM 256x256, BK=32, 8 waves, TRIPLE-buffer, read-ahead ------
// LDS 96KB: 3 bufs x [A 256x32 | B 256x32], row-XOR swizzled (granule ^ row&3).
// Counted vmcnt(4) (2-tile prefetch), 1 barrier/tile, frag read-ahead across tiles.
// mode 10: QKV merged (576 tiles: mat=wg/192; Q->d0/d1, K->d-swz d2, V->t+s-swz d3)
// mode 2 : linear f32 d0 (out projection, 192 tiles)
__global__ __launch_bounds__(512, 2) void gemm256r_kernel(
    const unsigned short* __restrict__ Aq, const unsigned short* __restrict__ Akv,
    const unsigned short* __restrict__ Wq, const unsigned short* __restrict__ Wk,
    const unsigned short* __restrict__ Wv,
    void* __restrict__ d0, void* __restrict__ d1,
    void* __restrict__ d2, void* __restrict__ d3, int mode) {
  __shared__ unsigned short lds3[3][16384];   // [buf][A 8192 | B 8192]

  const int tid = threadIdx.x;
  const int wid = tid >> 6, l = tid & 63;
  const int wm = wid >> 2, wn = wid & 3;      // wave tile 128x64
  const int fr = l & 15, fg = l >> 4;
  const int rc = (fg * 8) ^ ((fr & 3) << 3);  // swizzled frag k-offset (shorts)

  // XCD-chunked swizzle (grid % 8 == 0)
  const int cpx = gridDim.x >> 3;
  int wg = ((int)blockIdx.x & 7) * cpx + ((int)blockIdx.x >> 3);

  const unsigned short* A = Aq;
  const unsigned short* W = Wq;
  int emode = mode;
  if (mode == 10) {
    int mat = wg / 192; wg -= mat * 192;
    if (mat == 0)      { emode = 0; }
    else if (mat == 1) { emode = 3; A = Akv; W = Wk; }
    else               { emode = 1; A = Akv; W = Wv; }
  }
  const int bm = wg >> 3, bn = wg & 7;        // N=2048 -> 8 col tiles of 256

  // staging source: lane covers 16B granule (l&3), row wid*32+(l>>2) (+16 for i=1);
  // source granule pre-swizzled by row&3 so linear DMA lands in swizzled slots.
  const int lr = l >> 2;
  const int gsw = ((l & 3) ^ (lr & 3)) * 8;
  const unsigned short* gaBase = A + (size_t)(bm * 256 + wid * 32 + lr) * 2048 + gsw;
  const unsigned short* gbBase = W + (size_t)(bn * 256 + wid * 32 + lr) * 2048 + gsw;

#define STAGE(buf, kt) do {                                          \
    unsigned short* _da = &lds3[(buf)][wid * 1024];                  \
    unsigned short* _db = &lds3[(buf)][8192 + wid * 1024];           \
    const unsigned short* _sa = gaBase + (size_t)(kt) * 32;          \
    const unsigned short* _sb = gbBase + (size_t)(kt) * 32;          \
    gload_lds16(_sa,             _da);                               \
    gload_lds16(_sa + 16 * 2048, _da + 512);                         \
    gload_lds16(_sb,             _db);                               \
    gload_lds16(_sb + 16 * 2048, _db + 512);                         \
  } while (0)

  f32x4 acc[8][4] = {};
  bf16x8 af[8], bf01[2], bf23[2];

  // prologue: tiles 0 (buf0), 1 (buf1) in flight; wait tile0 only
  STAGE(0, 0);
  STAGE(1, 1);
  asm volatile("s_waitcnt vmcnt(4)" ::: "memory");
  __builtin_amdgcn_s_barrier();
  // read-ahead: tile0 phase-A fragments
#pragma unroll
  for (int mi = 0; mi < 8; ++mi)
    af[mi] = *(const bf16x8*)&lds3[0][(wm * 128 + mi * 16 + fr) * 32 + rc];
#pragma unroll
  for (int ni = 0; ni < 2; ++ni)
    bf01[ni] = *(const bf16x8*)&lds3[0][8192 + (wn * 64 + ni * 16 + fr) * 32 + rc];

  int cur = 0;
  for (int t = 0; t < 64; ++t) {
    // early: B ni2-3 reads + 2-ahead staging issue (overlap with phase-A MFMA)
#pragma unroll
    for (int ni = 0; ni < 2; ++ni)
      bf23[ni] = *(const bf16x8*)&lds3[cur][8192 + (wn * 64 + (ni + 2) * 16 + fr) * 32 + rc];
    if (t < 62) {
      int stg = cur + 2; if (stg >= 3) stg -= 3;
      STAGE(stg, t + 2);
    }

    // phase A: mi0-7 x ni0-1 (fragments pre-read last tile)
    __builtin_amdgcn_s_setprio(1);
#pragma unroll
    for (int mi = 0; mi < 8; ++mi)
#pragma unroll
      for (int ni = 0; ni < 2; ++ni)
        acc[mi][ni] = MFMA16(af[mi], bf01[ni], acc[mi][ni]);
    __builtin_amdgcn_s_setprio(0);

    // phase B: mi0-7 x ni2-3
    __builtin_amdgcn_s_setprio(1);
#pragma unroll
    for (int mi = 0; mi < 8; ++mi)
#pragma unroll
      for (int ni = 0; ni < 2; ++ni)
        acc[mi][ni + 2] = MFMA16(af[mi], bf23[ni], acc[mi][ni + 2]);
    __builtin_amdgcn_s_setprio(0);

    __builtin_amdgcn_sched_barrier(0);
    if (t < 62) {
      asm volatile("s_waitcnt vmcnt(4)" ::: "memory");   // tile t+1 landed; t+2 in flight
      __builtin_amdgcn_s_barrier();
    } else if (t == 62) {
      asm volatile("s_waitcnt vmcnt(0)" ::: "memory");   // tile 63 landed
      __builtin_amdgcn_s_barrier();
    }

    int nxt = cur + 1; if (nxt >= 3) nxt -= 3;
    if (t < 63) {
      // read-ahead tile t+1 phase-A fragments (af/bf01 regs free after phase B)
#pragma unroll
      for (int mi = 0; mi < 8; ++mi)
        af[mi] = *(const bf16x8*)&lds3[nxt][(wm * 128 + mi * 16 + fr) * 32 + rc];
#pragma unroll
      for (int ni = 0; ni < 2; ++ni)
        bf01[ni] = *(const bf16x8*)&lds3[nxt][8192 + (wn * 64 + ni * 16 + fr) * 32 + rc];
    }
    cur = nxt;
  }
#undef STAGE

  // ---- epilogue (identical geometry to round 9) ----
#pragma unroll
  for (int mi = 0; mi < 8; ++mi) {
    const int row0 = bm * 256 + wm * 128 + mi * 16 + fg * 4;
    if (emode == 1) {
      int b = row0 / 3072, s0 = row0 - b * 3072;
#pragma unroll
      for (int ni = 0; ni < 4; ++ni) {
        int col = bn * 256 + wn * 64 + ni * 16 + fr;
        int hh = col >> 7, d = col & 127;
        size_t bh = (size_t)(b * NH + hh);
        size_t idx = (bh * 128 + d) * (size_t)3072 + ((s0 & ~31) | ((s0 & 31) ^ ((d & 3) << 3)));
        uint2 pk;
        pk.x = cvtpk(acc[mi][ni][0], acc[mi][ni][1]);
        pk.y = cvtpk(acc[mi][ni][2], acc[mi][ni][3]);
        *(uint2*)((unsigned short*)d3 + idx) = pk;
      }
    } else {
#pragma unroll
      for (int r = 0; r < 4; ++r) {
        int row = row0 + r;
#pragma unroll
        for (int ni = 0; ni < 4; ++ni) {
          int col = bn * 256 + wn * 64 + ni * 16 + fr;
          float v = acc[mi][ni][r];
          if (emode == 2) {
            ((float*)d0)[(size_t)row * 2048 + col] = v;   // d_out is FLOAT32
          } else if (emode == 0) {
            int hh = col >> 7, d = col & 127;
            if (row < 4096) {
              int b = row >> 11, s = row & 2047;
              ((unsigned short*)d0)[((size_t)(b * NH + hh) * 2048 + s) * 128 + d] = f2bf(v);
            } else {
              int rr = row - 4096, b = rr >> 10, s = rr & 1023;
              ((unsigned short*)d1)[((size_t)(b * NH + hh) * 1024 + s) * 128 + d] = f2bf(v);
            }
          } else {  // emode == 3 : K, d-swizzled
            int b = row / 3072, s = row - b * 3072;
            int hh = col >> 7, d = col & 127;
            size_t bh = (size_t)(b * NH + hh);
            ((unsigned short*)d2)[(bh * 3072 + s) * 128 + (d ^ ((s & 7) << 3))] = f2bf(v);
          }
        }
      }
    }
  }
}

// ---------------- flash attention: dbuf K/V, KVBLK=32, counted-vmcnt -------------
// grid 768 (XCD-chunked). 4 waves x 32 q. LDS: Ks[2]|Vs[2]|P = 40KB.
__global__ __launch_bounds__(256, 3) void attn_kernel(
    const unsigned short* __restrict__ Qt, const unsigned short* __restrict__ Qi,
    const unsigned short* __restrict__ Kh, const unsigned short* __restrict__ Vt,
    unsigned short* __restrict__ AOt, unsigned short* __restrict__ AOi) {
  __shared__ unsigned short Sh[20480];  // Ks0|Ks1|Vs0|Vs1|P(4x1024)

  const int lin = blockIdx.x;
  const int w768 = (lin & 7) * 96 + (lin >> 3);
  const int qt24 = w768 % 24;
  const int hb   = w768 / 24;
  const int h = hb & 15, b = hb >> 4;
  const bool is_text = qt24 < 16;
  const int qt = is_text ? qt24 : qt24 - 16;
  const int Sq = is_text ? 2048 : 1024;
  const unsigned short* Qh = is_text ? Qt : Qi;
  unsigned short* AO = is_text ? AOt : AOi;

  const int tid = threadIdx.x;
  const int w = tid >> 6, l = tid & 63;
  const int fr = l & 15, fg = l >> 4;
  const size_t bh = (size_t)(b * NH + h);
  unsigned short* Pw = Sh + 16384 + w * 1024;   // per-wave [32 q][32 k]

  const unsigned short* Qbase = Qh + (bh * Sq + (size_t)qt * 128 + w * 32) * HD;
  bf16x8 qf[2][4];
#pragma unroll
  for (int h2 = 0; h2 < 2; ++h2)
#pragma unroll
    for (int c = 0; c < 4; ++c)
      qf[h2][c] = *(const bf16x8*)(Qbase + (h2 * 16 + fr) * HD + c * 32 + fg * 8);

  f32x4 o[2][8] = {};
  float m[2]    = {-1e30f, -1e30f};
  float lsum[2] = {0.f, 0.f};

  const unsigned short* Kb = Kh + bh * (size_t)SKV * HD;
  const unsigned short* Vb = Vt + bh * (size_t)HD * SKV;

  const int swk = (fr & 7) << 3;   // K d-swizzle (within 128)
  const int swv = (fr & 3) << 3;   // V s-swizzle (within 32) + P swizzle

#define STAGE_K(kt, half) do {                                                   \
    unsigned short* _d = Sh + (half) * 4096 + w * 1024;                          \
    const unsigned short* _s = Kb + (size_t)((kt) * 32 + w * 8 + (l >> 4)) * 128 \
                               + (l & 15) * 8;                                   \
    gload_lds16(_s, _d);                                                         \
    gload_lds16(_s + 4 * 128, _d + 512);                                         \
  } while (0)
#define STAGE_V(kt, half) do {                                                   \
    unsigned short* _d = Sh + 8192 + (half) * 4096 + w * 1024;                   \
    const unsigned short* _s = Vb + (size_t)(w * 32 + (l >> 2)) * SKV            \
                               + (kt) * 32 + (l & 3) * 8;                        \
    gload_lds16(_s, _d);                                                         \
    gload_lds16(_s + 16 * SKV, _d + 512);                                        \
  } while (0)

  STAGE_K(0, 0);
  for (int kt = 0; kt < 96; ++kt) {
    const int half = kt & 1;
    STAGE_V(kt, half);
    asm volatile("s_waitcnt vmcnt(2)" ::: "memory");   // K(kt) ready; V(kt) in flight
    __builtin_amdgcn_s_barrier();

    const unsigned short* Ksc = Sh + half * 4096;
    f32x4 sT[2][2] = {};
#pragma unroll
    for (int j = 0; j < 2; ++j) {
      const int krb = (j * 16 + fr) * 128;
#pragma unroll
      for (int c = 0; c < 4; ++c) {
        bf16x8 kf = *(const bf16x8*)&Ksc[krb + ((c * 32 + fg * 8) ^ swk)];
        sT[0][j] = MFMA16(kf, qf[0][c], sT[0][j]);
        sT[1][j] = MFMA16(kf, qf[1][c], sT[1][j]);
      }
    }
    if (kt < 95) STAGE_K(kt + 1, half ^ 1);

#pragma unroll
    for (int h2 = 0; h2 < 2; ++h2) {
      float tm = fmaxf(fmaxf(fmaxf(sT[h2][0][0], sT[h2][0][1]),
                             fmaxf(sT[h2][0][2], sT[h2][0][3])),
                       fmaxf(fmaxf(sT[h2][1][0], sT[h2][1][1]),
                             fmaxf(sT[h2][1][2], sT[h2][1][3])));
      tm = fmaxf(tm, __shfl_xor(tm, 16));
      tm = fmaxf(tm, __shfl_xor(tm, 32));
      if (__any(tm - m[h2] > DEFER_THR)) {
        float mn = fmaxf(m[h2], tm);
        float al = exp2hw(m[h2] - mn);
#pragma unroll
        for (int nt = 0; nt < 8; ++nt) {
          f32x4 t = o[h2][nt];
          t[0] *= al; t[1] *= al; t[2] *= al; t[3] *= al;
          o[h2][nt] = t;
        }
        lsum[h2] *= al;
        m[h2] = mn;
      }
      const float mm = m[h2];
      float p00 = exp2hw(sT[h2][0][0] - mm), p01 = exp2hw(sT[h2][0][1] - mm);
      float p02 = exp2hw(sT[h2][0][2] - mm), p03 = exp2hw(sT[h2][0][3] - mm);
      float p10 = exp2hw(sT[h2][1][0] - mm), p11 = exp2hw(sT[h2][1][1] - mm);
      float p12 = exp2hw(sT[h2][1][2] - mm), p13 = exp2hw(sT[h2][1][3] - mm);
      lsum[h2] += (p00 + p01 + p02 + p03) + (p10 + p11 + p12 + p13);
      unsigned short* prow = &Pw[(h2 * 16 + fr) * 32];
      uint2 w0; w0.x = cvtpk(p00, p01); w0.y = cvtpk(p02, p03);
      uint2 w1; w1.x = cvtpk(p10, p11); w1.y = cvtpk(p12, p13);
      *(uint2*)(prow + ((fg * 4) ^ swv))      = w0;
      *(uint2*)(prow + ((16 + fg * 4) ^ swv)) = w1;
    }

    if (kt < 95) asm volatile("s_waitcnt vmcnt(2)" ::: "memory");  // V(kt) ready
    else         asm volatile("s_waitcnt vmcnt(0)" ::: "memory");
    __builtin_amdgcn_s_barrier();

    asm volatile("s_waitcnt lgkmcnt(0)" ::: "memory");
    __builtin_amdgcn_sched_barrier(0);

    const unsigned short* Vsc = Sh + 8192 + half * 4096;
    bf16x8 pb[2];
#pragma unroll
    for (int h2 = 0; h2 < 2; ++h2)
      pb[h2] = *(const bf16x8*)&Pw[(h2 * 16 + fr) * 32 + ((fg * 8) ^ swv)];
#pragma unroll
    for (int nt = 0; nt < 8; ++nt) {
      bf16x8 vf = *(const bf16x8*)&Vsc[(nt * 16 + fr) * 32 + ((fg * 8) ^ swv)];
      o[0][nt] = MFMA16(vf, pb[0], o[0][nt]);
      o[1][nt] = MFMA16(vf, pb[1], o[1][nt]);
    }
    __builtin_amdgcn_s_barrier();
  }
#undef STAGE_K
#undef STAGE_V

  float inv[2];
#pragma unroll
  for (int h2 = 0; h2 < 2; ++h2) {
    float t = lsum[h2];
    t += __shfl_xor(t, 16);
    t += __shfl_xor(t, 32);
    inv[h2] = 1.0f / t;
  }
  unsigned short* Os = &Sh[w * 4096];
#pragma unroll
  for (int h2 = 0; h2 < 2; ++h2) {
    unsigned short* orow = &Os[(h2 * 16 + fr) * 128];
    const int sw8 = (fr & 7) << 3;
#pragma unroll
    for (int nt = 0; nt < 8; ++nt) {
      uint2 pk;
      pk.x = cvtpk(o[h2][nt][0] * inv[h2], o[h2][nt][1] * inv[h2]);
      pk.y = cvtpk(o[h2][nt][2] * inv[h2], o[h2][nt][3] * inv[h2]);
      *(uint2*)(orow + ((nt * 16 + fg * 4) ^ sw8)) = pk;
    }
  }
  asm volatile("s_waitcnt lgkmcnt(0)" ::: "memory");
  __builtin_amdgcn_sched_barrier(0);
  const int qr4 = l >> 4;
  const int dc = (l & 15) * 8;
  unsigned short* AObase = AO + ((size_t)b * Sq + (size_t)qt * 128 + w * 32) * D_MODEL + h * HD;
#pragma unroll
  for (int g = 0; g < 8; ++g) {
    const int row = g * 4 + qr4;
    bf16x8 v = *reinterpret_cast<const bf16x8*>(&Os[row * 128 + (dc ^ ((row & 7) << 3))]);
    *reinterpret_cast<bf16x8*>(&AObase[(size_t)row * D_MODEL + dc]) = v;
  }
}

// ---------------- host launch ----------------
extern "C" void kernel_launch(void* const* d_in, const int* in_sizes, int n_in,
                              void* d_out, int out_size, void* d_ws, size_t ws_size,
                              hipStream_t stream) {
  const float* q_text  = (const float*)d_in[0];
  const float* q_image = (const float*)d_in[1];
  const float* k_text  = (const float*)d_in[2];
  const float* k_image = (const float*)d_in[3];
  const float* Wq = (const float*)d_in[4];
  const float* Wk = (const float*)d_in[5];
  const float* Wv = (const float*)d_in[6];
  const float* Wo = (const float*)d_in[7];
  const float* ln_tg = (const float*)d_in[8];
  const float* ln_tb = (const float*)d_in[9];
  const float* ln_ig = (const float*)d_in[10];
  const float* ln_ib = (const float*)d_in[11];

  // workspace layout (bf16 elements)
  unsigned short* wq  = (unsigned short*)d_ws;
  unsigned short* wk  = wq  + 4194304;
  unsigned short* wv  = wk  + 4194304;
  unsigned short* wo  = wv  + 4194304;
  unsigned short* xqt = wo  + 4194304;   // LN'd q_text  [4096,2048]; later AO_text
  unsigned short* xqi = xqt + 8388608;   // LN'd q_image [2048,2048]; later AO_image
  unsigned short* xk  = xqi + 4194304;   // LN'd concat k [2,3072,2048]
  unsigned short* qht = xk  + 12582912;  // [2,16,2048,128]
  unsigned short* qhi = qht + 8388608;   // [2,16,1024,128]
  unsigned short* kh  = qhi + 4194304;   // [2,16,3072,128] (d-swizzled)
  unsigned short* vt  = kh  + 12582912;  // [2,16,128,3072] (s-swizzled, 32-groups)
  const size_t needed = (size_t)(vt + 12582912 - wq) * 2;
  if (ws_size < needed) return;

  cvt_w_kernel<<<dim3(2048, 4), 256, 0, stream>>>(Wq, Wk, Wv, Wo, wq);

  ln_kernel<<<4096, 256, 0, stream>>>(q_text,  ln_tg, ln_tb, xqt, 2048, 2048, 0);
  ln_kernel<<<2048, 256, 0, stream>>>(q_image, ln_ig, ln_ib, xqi, 1024, 1024, 0);
  ln_kernel<<<4096, 256, 0, stream>>>(k_text,  ln_tg, ln_tb, xk, 2048, 3072, 0);
  ln_kernel<<<2048, 256, 0, stream>>>(k_image, ln_ig, ln_ib, xk, 1024, 3072, 2048);

  // Q+K+V in ONE dispatch: 576 tiles of 256^2
  gemm256r_kernel<<<576, 512, 0, stream>>>(xqt, xk, wq, wk, wv, qht, qhi, kh, vt, 10);

  attn_kernel<<<768, 256, 0, stream>>>(qht, qhi, kh, vt, xqt, xqi);

  // out projection: 192 tiles, f32 straight into d_out
  gemm256r_kernel<<<192, 512, 0, stream>>>(xqt, nullptr, wo, nullptr, nullptr,
                                           d_out, nullptr, nullptr, nullptr, 2);
}

// Round 11
// 502.973 us; speedup vs baseline: 1.0242x; 1.0242x over previous
//
#include <hip/hip_runtime.h>

// ---------------- types / helpers ----------------
typedef __attribute__((ext_vector_type(8))) short bf16x8;   // 8 bf16 (4 VGPRs)
typedef __attribute__((ext_vector_type(4))) float f32x4;    // MFMA accum
typedef __attribute__((ext_vector_type(8))) unsigned short u16x8;

#define D_MODEL 2048
#define NH 16
#define HD 128
#define SKV 3072
#define QK_SCALE 0.08838834764831845f  // 128^-0.5
#define LOG2E 1.4426950408889634f
#define DEFER_THR 11.5413f             // 8 * log2(e)

__device__ __forceinline__ unsigned short f2bf(float f) {
  unsigned int u = __float_as_uint(f);
  u += 0x7fffu + ((u >> 16) & 1u);     // RNE, finite inputs only
  return (unsigned short)(u >> 16);
}
__device__ __forceinline__ float exp2hw(float x) {
  float r; asm("v_exp_f32 %0, %1" : "=v"(r) : "v"(x)); return r;
}
__device__ __forceinline__ unsigned int cvtpk(float lo, float hi) {
  unsigned int r; asm("v_cvt_pk_bf16_f32 %0, %1, %2" : "=v"(r) : "v"(lo), "v"(hi)); return r;
}

typedef __attribute__((address_space(1))) void as1_void;
typedef __attribute__((address_space(3))) void as3_void;
__device__ __forceinline__ void gload_lds16(const void* g, void* l) {
  __builtin_amdgcn_global_load_lds((as1_void*)g, (as3_void*)l, 16, 0, 0);
}

#define MFMA16(a, b, c) __builtin_amdgcn_mfma_f32_16x16x32_bf16((a), (b), (c), 0, 0, 0)

// ---------------- weight convert: all 4 weights in one dispatch ----------------
__global__ __launch_bounds__(256) void cvt_w_kernel(
    const float* __restrict__ s0, const float* __restrict__ s1,
    const float* __restrict__ s2, const float* __restrict__ s3,
    unsigned short* __restrict__ dstbase) {
  const int y = blockIdx.y;
  const float* src = (y == 0) ? s0 : (y == 1) ? s1 : (y == 2) ? s2 : s3;
  const float scale = (y == 0) ? (QK_SCALE * LOG2E) : 1.0f;   // fold softmax+log2e into Wq
  unsigned short* dst = dstbase + (size_t)y * 4194304;
  int i = blockIdx.x * 256 + threadIdx.x;
  const float4* s = (const float4*)src + (size_t)i * 2;
  float4 a = s[0], b = s[1];
  u16x8 r;
  r[0] = f2bf(a.x * scale); r[1] = f2bf(a.y * scale);
  r[2] = f2bf(a.z * scale); r[3] = f2bf(a.w * scale);
  r[4] = f2bf(b.x * scale); r[5] = f2bf(b.y * scale);
  r[6] = f2bf(b.z * scale); r[7] = f2bf(b.w * scale);
  *((u16x8*)dst + i) = r;
}

// ---------------- LayerNorm -> bf16 (with row remap for K concat) ----------------
__global__ __launch_bounds__(256) void ln_kernel(
    const float* __restrict__ x, const float* __restrict__ gw,
    const float* __restrict__ bw, unsigned short* __restrict__ out,
    int spb, int orpb, int obase) {
  const int row = blockIdx.x;
  const int t = threadIdx.x;
  const int b = row / spb, s = row - b * spb;
  const float* xr = x + (size_t)row * D_MODEL;
  unsigned short* orow = out + ((size_t)b * orpb + obase + s) * D_MODEL;

  float4 v0 = *(const float4*)(xr + t * 8);
  float4 v1 = *(const float4*)(xr + t * 8 + 4);
  float sum = v0.x + v0.y + v0.z + v0.w + v1.x + v1.y + v1.z + v1.w;
  float sq  = v0.x*v0.x + v0.y*v0.y + v0.z*v0.z + v0.w*v0.w
            + v1.x*v1.x + v1.y*v1.y + v1.z*v1.z + v1.w*v1.w;
#pragma unroll
  for (int o = 32; o > 0; o >>= 1) {
    sum += __shfl_down(sum, o);
    sq  += __shfl_down(sq, o);
  }
  __shared__ float red[8];
  const int wv = t >> 6, l = t & 63;
  if (l == 0) { red[wv] = sum; red[4 + wv] = sq; }
  __syncthreads();
  sum = red[0] + red[1] + red[2] + red[3];
  sq  = red[4] + red[5] + red[6] + red[7];
  const float mu = sum * (1.0f / 2048.0f);
  const float var = sq * (1.0f / 2048.0f) - mu * mu;
  const float rs = rsqrtf(var + 1e-5f);

  float4 g0 = *(const float4*)(gw + t * 8);
  float4 g1 = *(const float4*)(gw + t * 8 + 4);
  float4 b0 = *(const float4*)(bw + t * 8);
  float4 b1 = *(const float4*)(bw + t * 8 + 4);
  u16x8 r;
  r[0] = f2bf((v0.x - mu) * rs * g0.x + b0.x);
  r[1] = f2bf((v0.y - mu) * rs * g0.y + b0.y);
  r[2] = f2bf((v0.z - mu) * rs * g0.z + b0.z);
  r[3] = f2bf((v0.w - mu) * rs * g0.w + b0.w);
  r[4] = f2bf((v1.x - mu) * rs * g1.x + b1.x);
  r[5] = f2bf((v1.y - mu) * rs * g1.y + b1.y);
  r[6] = f2bf((v1.z - mu) * rs * g1.z + b1.z);
  r[7] = f2bf((v1.w - mu) * rs * g1.w + b1.w);
  *(u16x8*)(orow + t * 8) = r;
}

// ---------------- GEMM 256x128, BK=32, 4 waves, TRIPLE-buffer, read-ahead ------
// 2 blocks/CU (LDS 72KB, regs 256/wave exactly). Same per-wave schedule as r10.
// mode 10: QKV merged (1152 tiles: mat=wg/384; Q->d0/d1, K->d-swz d2, V->t+s-swz d3)
// mode 2 : linear f32 d0 (out projection, 384 tiles)
__global__ __launch_bounds__(256, 2) void gemm256x_kernel(
    const unsigned short* __restrict__ Aq, const unsigned short* __restrict__ Akv,
    const unsigned short* __restrict__ Wq, const unsigned short* __restrict__ Wk,
    const unsigned short* __restrict__ Wv,
    void* __restrict__ d0, void* __restrict__ d1,
    void* __restrict__ d2, void* __restrict__ d3, int mode) {
  __shared__ unsigned short lds3[3][12288];   // [buf][A 8192 | B 4096] shorts = 24KB

  const int tid = threadIdx.x;
  const int wid = tid >> 6, l = tid & 63;
  const int wm = wid >> 1, wn = wid & 1;      // 2M x 2N waves; wave tile 128x64
  const int fr = l & 15, fg = l >> 4;
  const int rc = (fg * 8) ^ ((fr & 3) << 3);  // swizzled frag k-offset (shorts)

  // XCD-chunked swizzle (grid % 8 == 0)
  const int cpx = gridDim.x >> 3;
  int wg = ((int)blockIdx.x & 7) * cpx + ((int)blockIdx.x >> 3);

  const unsigned short* A = Aq;
  const unsigned short* W = Wq;
  int emode = mode;
  if (mode == 10) {
    int mat = wg / 384; wg -= mat * 384;
    if (mat == 0)      { emode = 0; }
    else if (mat == 1) { emode = 3; A = Akv; W = Wk; }
    else               { emode = 1; A = Akv; W = Wv; }
  }
  const int bm = wg >> 4, bn = wg & 15;       // N=2048 -> 16 col tiles of 128

  // staging source: lane covers 16B granule (l&3) of row lr=l>>2 within a 16-row
  // chunk; source granule pre-swizzled by row&3 (matches frag-read rc swizzle).
  const int lr = l >> 2;
  const int gsw = ((l & 3) ^ (lr & 3)) * 8;
  const unsigned short* gaBase = A + (size_t)(bm * 256 + wid * 64 + lr) * 2048 + gsw;
  const unsigned short* gbBase = W + (size_t)(bn * 128 + wid * 32 + lr) * 2048 + gsw;

#define STAGE(buf, kt) do {                                          \
    unsigned short* _da = &lds3[(buf)][wid * 2048];                  \
    unsigned short* _db = &lds3[(buf)][8192 + wid * 1024];           \
    const unsigned short* _sa = gaBase + (size_t)(kt) * 32;          \
    const unsigned short* _sb = gbBase + (size_t)(kt) * 32;          \
    gload_lds16(_sa,             _da);                               \
    gload_lds16(_sa + 16 * 2048, _da + 512);                         \
    gload_lds16(_sa + 32 * 2048, _da + 1024);                        \
    gload_lds16(_sa + 48 * 2048, _da + 1536);                        \
    gload_lds16(_sb,             _db);                               \
    gload_lds16(_sb + 16 * 2048, _db + 512);                         \
  } while (0)

  f32x4 acc[8][4] = {};
  bf16x8 af[8], bf01[2], bf23[2];

  // prologue: tiles 0 (buf0), 1 (buf1) in flight; wait tile0 only (6 loads pending)
  STAGE(0, 0);
  STAGE(1, 1);
  asm volatile("s_waitcnt vmcnt(6)" ::: "memory");
  __builtin_amdgcn_s_barrier();
  // read-ahead: tile0 phase-A fragments
#pragma unroll
  for (int mi = 0; mi < 8; ++mi)
    af[mi] = *(const bf16x8*)&lds3[0][(wm * 128 + mi * 16 + fr) * 32 + rc];
#pragma unroll
  for (int ni = 0; ni < 2; ++ni)
    bf01[ni] = *(const bf16x8*)&lds3[0][8192 + (wn * 64 + ni * 16 + fr) * 32 + rc];

  int cur = 0;
  for (int t = 0; t < 64; ++t) {
    // early: B ni2-3 reads + 2-ahead staging issue (overlap with phase-A MFMA)
#pragma unroll
    for (int ni = 0; ni < 2; ++ni)
      bf23[ni] = *(const bf16x8*)&lds3[cur][8192 + (wn * 64 + (ni + 2) * 16 + fr) * 32 + rc];
    if (t < 62) {
      int stg = cur + 2; if (stg >= 3) stg -= 3;
      STAGE(stg, t + 2);
    }

    // phase A: mi0-7 x ni0-1
    __builtin_amdgcn_s_setprio(1);
#pragma unroll
    for (int mi = 0; mi < 8; ++mi)
#pragma unroll
      for (int ni = 0; ni < 2; ++ni)
        acc[mi][ni] = MFMA16(af[mi], bf01[ni], acc[mi][ni]);
    __builtin_amdgcn_s_setprio(0);

    // phase B: mi0-7 x ni2-3
    __builtin_amdgcn_s_setprio(1);
#pragma unroll
    for (int mi = 0; mi < 8; ++mi)
#pragma unroll
      for (int ni = 0; ni < 2; ++ni)
        acc[mi][ni + 2] = MFMA16(af[mi], bf23[ni], acc[mi][ni + 2]);
    __builtin_amdgcn_s_setprio(0);

    __builtin_amdgcn_sched_barrier(0);
    if (t < 62) {
      asm volatile("s_waitcnt vmcnt(6)" ::: "memory");   // tile t+1 landed; t+2 in flight
      __builtin_amdgcn_s_barrier();
    } else if (t == 62) {
      asm volatile("s_waitcnt vmcnt(0)" ::: "memory");   // tile 63 landed
      __builtin_amdgcn_s_barrier();
    }

    int nxt = cur + 1; if (nxt >= 3) nxt -= 3;
    if (t < 63) {
      // read-ahead tile t+1 phase-A fragments
#pragma unroll
      for (int mi = 0; mi < 8; ++mi)
        af[mi] = *(const bf16x8*)&lds3[nxt][(wm * 128 + mi * 16 + fr) * 32 + rc];
#pragma unroll
      for (int ni = 0; ni < 2; ++ni)
        bf01[ni] = *(const bf16x8*)&lds3[nxt][8192 + (wn * 64 + ni * 16 + fr) * 32 + rc];
    }
    cur = nxt;
  }
#undef STAGE

  // ---- epilogue ----
#pragma unroll
  for (int mi = 0; mi < 8; ++mi) {
    const int row0 = bm * 256 + wm * 128 + mi * 16 + fg * 4;
    if (emode == 1) {
      int b = row0 / 3072, s0 = row0 - b * 3072;
#pragma unroll
      for (int ni = 0; ni < 4; ++ni) {
        int col = bn * 128 + wn * 64 + ni * 16 + fr;
        int hh = col >> 7, d = col & 127;
        size_t bh = (size_t)(b * NH + hh);
        size_t idx = (bh * 128 + d) * (size_t)3072 + ((s0 & ~31) | ((s0 & 31) ^ ((d & 3) << 3)));
        uint2 pk;
        pk.x = cvtpk(acc[mi][ni][0], acc[mi][ni][1]);
        pk.y = cvtpk(acc[mi][ni][2], acc[mi][ni][3]);
        *(uint2*)((unsigned short*)d3 + idx) = pk;
      }
    } else {
#pragma unroll
      for (int r = 0; r < 4; ++r) {
        int row = row0 + r;
#pragma unroll
        for (int ni = 0; ni < 4; ++ni) {
          int col = bn * 128 + wn * 64 + ni * 16 + fr;
          float v = acc[mi][ni][r];
          if (emode == 2) {
            ((float*)d0)[(size_t)row * 2048 + col] = v;   // d_out is FLOAT32
          } else if (emode == 0) {
            int hh = col >> 7, d = col & 127;
            if (row < 4096) {
              int b = row >> 11, s = row & 2047;
              ((unsigned short*)d0)[((size_t)(b * NH + hh) * 2048 + s) * 128 + d] = f2bf(v);
            } else {
              int rr = row - 4096, b = rr >> 10, s = rr & 1023;
              ((unsigned short*)d1)[((size_t)(b * NH + hh) * 1024 + s) * 128 + d] = f2bf(v);
            }
          } else {  // emode == 3 : K, d-swizzled
            int b = row / 3072, s = row - b * 3072;
            int hh = col >> 7, d = col & 127;
            size_t bh = (size_t)(b * NH + hh);
            ((unsigned short*)d2)[(bh * 3072 + s) * 128 + (d ^ ((s & 7) << 3))] = f2bf(v);
          }
        }
      }
    }
  }
}

// ---------------- flash attention: dbuf K/V, KVBLK=32, counted-vmcnt -------------
// grid 768 (XCD-chunked). 4 waves x 32 q. LDS: Ks[2]|Vs[2]|P = 40KB.
__global__ __launch_bounds__(256, 3) void attn_kernel(
    const unsigned short* __restrict__ Qt, const unsigned short* __restrict__ Qi,
    const unsigned short* __restrict__ Kh, const unsigned short* __restrict__ Vt,
    unsigned short* __restrict__ AOt, unsigned short* __restrict__ AOi) {
  __shared__ unsigned short Sh[20480];  // Ks0|Ks1|Vs0|Vs1|P(4x1024)

  const int lin = blockIdx.x;
  const int w768 = (lin & 7) * 96 + (lin >> 3);
  const int qt24 = w768 % 24;
  const int hb   = w768 / 24;
  const int h = hb & 15, b = hb >> 4;
  const bool is_text = qt24 < 16;
  const int qt = is_text ? qt24 : qt24 - 16;
  const int Sq = is_text ? 2048 : 1024;
  const unsigned short* Qh = is_text ? Qt : Qi;
  unsigned short* AO = is_text ? AOt : AOi;

  const int tid = threadIdx.x;
  const int w = tid >> 6, l = tid & 63;
  const int fr = l & 15, fg = l >> 4;
  const size_t bh = (size_t)(b * NH + h);
  unsigned short* Pw = Sh + 16384 + w * 1024;   // per-wave [32 q][32 k]

  const unsigned short* Qbase = Qh + (bh * Sq + (size_t)qt * 128 + w * 32) * HD;
  bf16x8 qf[2][4];
#pragma unroll
  for (int h2 = 0; h2 < 2; ++h2)
#pragma unroll
    for (int c = 0; c < 4; ++c)
      qf[h2][c] = *(const bf16x8*)(Qbase + (h2 * 16 + fr) * HD + c * 32 + fg * 8);

  f32x4 o[2][8] = {};
  float m[2]    = {-1e30f, -1e30f};
  float lsum[2] = {0.f, 0.f};

  const unsigned short* Kb = Kh + bh * (size_t)SKV * HD;
  const unsigned short* Vb = Vt + bh * (size_t)HD * SKV;

  const int swk = (fr & 7) << 3;   // K d-swizzle (within 128)
  const int swv = (fr & 3) << 3;   // V s-swizzle (within 32) + P swizzle

#define STAGE_K(kt, half) do {                                                   \
    unsigned short* _d = Sh + (half) * 4096 + w * 1024;                          \
    const unsigned short* _s = Kb + (size_t)((kt) * 32 + w * 8 + (l >> 4)) * 128 \
                               + (l & 15) * 8;                                   \
    gload_lds16(_s, _d);                                                         \
    gload_lds16(_s + 4 * 128, _d + 512);                                         \
  } while (0)
#define STAGE_V(kt, half) do {                                                   \
    unsigned short* _d = Sh + 8192 + (half) * 4096 + w * 1024;                   \
    const unsigned short* _s = Vb + (size_t)(w * 32 + (l >> 2)) * SKV            \
                               + (kt) * 32 + (l & 3) * 8;                        \
    gload_lds16(_s, _d);                                                         \
    gload_lds16(_s + 16 * SKV, _d + 512);                                        \
  } while (0)

  STAGE_K(0, 0);
  for (int kt = 0; kt < 96; ++kt) {
    const int half = kt & 1;
    STAGE_V(kt, half);
    asm volatile("s_waitcnt vmcnt(2)" ::: "memory");   // K(kt) ready; V(kt) in flight
    __builtin_amdgcn_s_barrier();

    const unsigned short* Ksc = Sh + half * 4096;
    f32x4 sT[2][2] = {};
#pragma unroll
    for (int j = 0; j < 2; ++j) {
      const int krb = (j * 16 + fr) * 128;
#pragma unroll
      for (int c = 0; c < 4; ++c) {
        bf16x8 kf = *(const bf16x8*)&Ksc[krb + ((c * 32 + fg * 8) ^ swk)];
        sT[0][j] = MFMA16(kf, qf[0][c], sT[0][j]);
        sT[1][j] = MFMA16(kf, qf[1][c], sT[1][j]);
      }
    }
    if (kt < 95) STAGE_K(kt + 1, half ^ 1);

#pragma unroll
    for (int h2 = 0; h2 < 2; ++h2) {
      float tm = fmaxf(fmaxf(fmaxf(sT[h2][0][0], sT[h2][0][1]),
                             fmaxf(sT[h2][0][2], sT[h2][0][3])),
                       fmaxf(fmaxf(sT[h2][1][0], sT[h2][1][1]),
                             fmaxf(sT[h2][1][2], sT[h2][1][3])));
      tm = fmaxf(tm, __shfl_xor(tm, 16));
      tm = fmaxf(tm, __shfl_xor(tm, 32));
      if (__any(tm - m[h2] > DEFER_THR)) {
        float mn = fmaxf(m[h2], tm);
        float al = exp2hw(m[h2] - mn);
#pragma unroll
        for (int nt = 0; nt < 8; ++nt) {
          f32x4 t = o[h2][nt];
          t[0] *= al; t[1] *= al; t[2] *= al; t[3] *= al;
          o[h2][nt] = t;
        }
        lsum[h2] *= al;
        m[h2] = mn;
      }
      const float mm = m[h2];
      float p00 = exp2hw(sT[h2][0][0] - mm), p01 = exp2hw(sT[h2][0][1] - mm);
      float p02 = exp2hw(sT[h2][0][2] - mm), p03 = exp2hw(sT[h2][0][3] - mm);
      float p10 = exp2hw(sT[h2][1][0] - mm), p11 = exp2hw(sT[h2][1][1] - mm);
      float p12 = exp2hw(sT[h2][1][2] - mm), p13 = exp2hw(sT[h2][1][3] - mm);
      lsum[h2] += (p00 + p01 + p02 + p03) + (p10 + p11 + p12 + p13);
      unsigned short* prow = &Pw[(h2 * 16 + fr) * 32];
      uint2 w0; w0.x = cvtpk(p00, p01); w0.y = cvtpk(p02, p03);
      uint2 w1; w1.x = cvtpk(p10, p11); w1.y = cvtpk(p12, p13);
      *(uint2*)(prow + ((fg * 4) ^ swv))      = w0;
      *(uint2*)(prow + ((16 + fg * 4) ^ swv)) = w1;
    }

    if (kt < 95) asm volatile("s_waitcnt vmcnt(2)" ::: "memory");  // V(kt) ready
    else         asm volatile("s_waitcnt vmcnt(0)" ::: "memory");
    __builtin_amdgcn_s_barrier();

    asm volatile("s_waitcnt lgkmcnt(0)" ::: "memory");
    __builtin_amdgcn_sched_barrier(0);

    const unsigned short* Vsc = Sh + 8192 + half * 4096;
    bf16x8 pb[2];
#pragma unroll
    for (int h2 = 0; h2 < 2; ++h2)
      pb[h2] = *(const bf16x8*)&Pw[(h2 * 16 + fr) * 32 + ((fg * 8) ^ swv)];
#pragma unroll
    for (int nt = 0; nt < 8; ++nt) {
      bf16x8 vf = *(const bf16x8*)&Vsc[(nt * 16 + fr) * 32 + ((fg * 8) ^ swv)];
      o[0][nt] = MFMA16(vf, pb[0], o[0][nt]);
      o[1][nt] = MFMA16(vf, pb[1], o[1][nt]);
    }
    __builtin_amdgcn_s_barrier();
  }
#undef STAGE_K
#undef STAGE_V

  float inv[2];
#pragma unroll
  for (int h2 = 0; h2 < 2; ++h2) {
    float t = lsum[h2];
    t += __shfl_xor(t, 16);
    t += __shfl_xor(t, 32);
    inv[h2] = 1.0f / t;
  }
  unsigned short* Os = &Sh[w * 4096];
#pragma unroll
  for (int h2 = 0; h2 < 2; ++h2) {
    unsigned short* orow = &Os[(h2 * 16 + fr) * 128];
    const int sw8 = (fr & 7) << 3;
#pragma unroll
    for (int nt = 0; nt < 8; ++nt) {
      uint2 pk;
      pk.x = cvtpk(o[h2][nt][0] * inv[h2], o[h2][nt][1] * inv[h2]);
      pk.y = cvtpk(o[h2][nt][2] * inv[h2], o[h2][nt][3] * inv[h2]);
      *(uint2*)(orow + ((nt * 16 + fg * 4) ^ sw8)) = pk;
    }
  }
  asm volatile("s_waitcnt lgkmcnt(0)" ::: "memory");
  __builtin_amdgcn_sched_barrier(0);
  const int qr4 = l >> 4;
  const int dc = (l & 15) * 8;
  unsigned short* AObase = AO + ((size_t)b * Sq + (size_t)qt * 128 + w * 32) * D_MODEL + h * HD;
#pragma unroll
  for (int g = 0; g < 8; ++g) {
    const int row = g * 4 + qr4;
    bf16x8 v = *reinterpret_cast<const bf16x8*>(&Os[row * 128 + (dc ^ ((row & 7) << 3))]);
    *reinterpret_cast<bf16x8*>(&AObase[(size_t)row * D_MODEL + dc]) = v;
  }
}

// ---------------- host launch ----------------
extern "C" void kernel_launch(void* const* d_in, const int* in_sizes, int n_in,
                              void* d_out, int out_size, void* d_ws, size_t ws_size,
                              hipStream_t stream) {
  const float* q_text  = (const float*)d_in[0];
  const float* q_image = (const float*)d_in[1];
  const float* k_text  = (const float*)d_in[2];
  const float* k_image = (const float*)d_in[3];
  const float* Wq = (const float*)d_in[4];
  const float* Wk = (const float*)d_in[5];
  const float* Wv = (const float*)d_in[6];
  const float* Wo = (const float*)d_in[7];
  const float* ln_tg = (const float*)d_in[8];
  const float* ln_tb = (const float*)d_in[9];
  const float* ln_ig = (const float*)d_in[10];
  const float* ln_ib = (const float*)d_in[11];

  // workspace layout (bf16 elements)
  unsigned short* wq  = (unsigned short*)d_ws;
  unsigned short* wk  = wq  + 4194304;
  unsigned short* wv  = wk  + 4194304;
  unsigned short* wo  = wv  + 4194304;
  unsigned short* xqt = wo  + 4194304;   // LN'd q_text  [4096,2048]; later AO_text
  unsigned short* xqi = xqt + 8388608;   // LN'd q_image [2048,2048]; later AO_image
  unsigned short* xk  = xqi + 4194304;   // LN'd concat k [2,3072,2048]
  unsigned short* qht = xk  + 12582912;  // [2,16,2048,128]
  unsigned short* qhi = qht + 8388608;   // [2,16,1024,128]
  unsigned short* kh  = qhi + 4194304;   // [2,16,3072,128] (d-swizzled)
  unsigned short* vt  = kh  + 12582912;  // [2,16,128,3072] (s-swizzled, 32-groups)
  const size_t needed = (size_t)(vt + 12582912 - wq) * 2;
  if (ws_size < needed) return;

  cvt_w_kernel<<<dim3(2048, 4), 256, 0, stream>>>(Wq, Wk, Wv, Wo, wq);

  ln_kernel<<<4096, 256, 0, stream>>>(q_text,  ln_tg, ln_tb, xqt, 2048, 2048, 0);
  ln_kernel<<<2048, 256, 0, stream>>>(q_image, ln_ig, ln_ib, xqi, 1024, 1024, 0);
  ln_kernel<<<4096, 256, 0, stream>>>(k_text,  ln_tg, ln_tb, xk, 2048, 3072, 0);
  ln_kernel<<<2048, 256, 0, stream>>>(k_image, ln_ig, ln_ib, xk, 1024, 3072, 2048);

  // Q+K+V in ONE dispatch: 1152 tiles of 256x128, 2 blocks/CU
  gemm256x_kernel<<<1152, 256, 0, stream>>>(xqt, xk, wq, wk, wv, qht, qhi, kh, vt, 10);

  attn_kernel<<<768, 256, 0, stream>>>(qht, qhi, kh, vt, xqt, xqi);

  // out projection: 384 tiles, f32 straight into d_out
  gemm256x_kernel<<<384, 256, 0, stream>>>(xqt, nullptr, wo, nullptr, nullptr,
                                           d_out, nullptr, nullptr, nullptr, 2);
}

// Round 12
// 495.818 us; speedup vs baseline: 1.0390x; 1.0144x over previous
//
#include <hip/hip_runtime.h>

// ---------------- types / helpers ----------------
typedef __attribute__((ext_vector_type(8))) short bf16x8;   // 8 bf16 (4 VGPRs)
typedef __attribute__((ext_vector_type(4))) float f32x4;    // MFMA accum
typedef __attribute__((ext_vector_type(8))) unsigned short u16x8;

#define D_MODEL 2048
#define NH 16
#define HD 128
#define SKV 3072
#define QK_SCALE 0.08838834764831845f  // 128^-0.5
#define LOG2E 1.4426950408889634f
#define DEFER_THR 11.5413f             // 8 * log2(e)

__device__ __forceinline__ unsigned short f2bf(float f) {
  unsigned int u = __float_as_uint(f);
  u += 0x7fffu + ((u >> 16) & 1u);     // RNE, finite inputs only
  return (unsigned short)(u >> 16);
}
__device__ __forceinline__ float exp2hw(float x) {
  float r; asm("v_exp_f32 %0, %1" : "=v"(r) : "v"(x)); return r;
}
__device__ __forceinline__ unsigned int cvtpk(float lo, float hi) {
  unsigned int r; asm("v_cvt_pk_bf16_f32 %0, %1, %2" : "=v"(r) : "v"(lo), "v"(hi)); return r;
}

typedef __attribute__((address_space(1))) void as1_void;
typedef __attribute__((address_space(3))) void as3_void;
__device__ __forceinline__ void gload_lds16(const void* g, void* l) {
  __builtin_amdgcn_global_load_lds((as1_void*)g, (as3_void*)l, 16, 0, 0);
}

#define MFMA16(a, b, c) __builtin_amdgcn_mfma_f32_16x16x32_bf16((a), (b), (c), 0, 0, 0)

// ---------------- weight convert: all 4 weights in one dispatch ----------------
__global__ __launch_bounds__(256) void cvt_w_kernel(
    const float* __restrict__ s0, const float* __restrict__ s1,
    const float* __restrict__ s2, const float* __restrict__ s3,
    unsigned short* __restrict__ dstbase) {
  const int y = blockIdx.y;
  const float* src = (y == 0) ? s0 : (y == 1) ? s1 : (y == 2) ? s2 : s3;
  const float scale = (y == 0) ? (QK_SCALE * LOG2E) : 1.0f;   // fold softmax+log2e into Wq
  unsigned short* dst = dstbase + (size_t)y * 4194304;
  int i = blockIdx.x * 256 + threadIdx.x;
  const float4* s = (const float4*)src + (size_t)i * 2;
  float4 a = s[0], b = s[1];
  u16x8 r;
  r[0] = f2bf(a.x * scale); r[1] = f2bf(a.y * scale);
  r[2] = f2bf(a.z * scale); r[3] = f2bf(a.w * scale);
  r[4] = f2bf(b.x * scale); r[5] = f2bf(b.y * scale);
  r[6] = f2bf(b.z * scale); r[7] = f2bf(b.w * scale);
  *((u16x8*)dst + i) = r;
}

// ---------------- LayerNorm: all 4 tensors in ONE dispatch ----------------
__global__ __launch_bounds__(256) void ln_all_kernel(
    const float* __restrict__ qt, const float* __restrict__ qi,
    const float* __restrict__ ktx, const float* __restrict__ kix,
    const float* __restrict__ gt, const float* __restrict__ bt,
    const float* __restrict__ gi, const float* __restrict__ bi,
    unsigned short* __restrict__ xqt, unsigned short* __restrict__ xqi,
    unsigned short* __restrict__ xk) {
  const int rid = blockIdx.x;
  const int t = threadIdx.x;
  const float* src; const float* gw; const float* bw; unsigned short* dst;
  if (rid < 4096)      { src = qt + (size_t)rid * 2048; gw = gt; bw = bt; dst = xqt + (size_t)rid * 2048; }
  else if (rid < 6144) { int r = rid - 4096; src = qi + (size_t)r * 2048; gw = gi; bw = bi; dst = xqi + (size_t)r * 2048; }
  else if (rid < 10240){ int r = rid - 6144; src = ktx + (size_t)r * 2048; gw = gt; bw = bt;
                         int b = r >> 11, s = r & 2047; dst = xk + ((size_t)b * 3072 + s) * 2048; }
  else                 { int r = rid - 10240; src = kix + (size_t)r * 2048; gw = gi; bw = bi;
                         int b = r >> 10, s = r & 1023; dst = xk + ((size_t)b * 3072 + 2048 + s) * 2048; }

  float4 v0 = *(const float4*)(src + t * 8);
  float4 v1 = *(const float4*)(src + t * 8 + 4);
  float sum = v0.x + v0.y + v0.z + v0.w + v1.x + v1.y + v1.z + v1.w;
  float sq  = v0.x*v0.x + v0.y*v0.y + v0.z*v0.z + v0.w*v0.w
            + v1.x*v1.x + v1.y*v1.y + v1.z*v1.z + v1.w*v1.w;
#pragma unroll
  for (int o = 32; o > 0; o >>= 1) {
    sum += __shfl_down(sum, o);
    sq  += __shfl_down(sq, o);
  }
  __shared__ float red[8];
  const int wv = t >> 6, l = t & 63;
  if (l == 0) { red[wv] = sum; red[4 + wv] = sq; }
  __syncthreads();
  sum = red[0] + red[1] + red[2] + red[3];
  sq  = red[4] + red[5] + red[6] + red[7];
  const float mu = sum * (1.0f / 2048.0f);
  const float var = sq * (1.0f / 2048.0f) - mu * mu;
  const float rs = rsqrtf(var + 1e-5f);

  float4 g0 = *(const float4*)(gw + t * 8);
  float4 g1 = *(const float4*)(gw + t * 8 + 4);
  float4 b0 = *(const float4*)(bw + t * 8);
  float4 b1 = *(const float4*)(bw + t * 8 + 4);
  u16x8 r;
  r[0] = f2bf((v0.x - mu) * rs * g0.x + b0.x);
  r[1] = f2bf((v0.y - mu) * rs * g0.y + b0.y);
  r[2] = f2bf((v0.z - mu) * rs * g0.z + b0.z);
  r[3] = f2bf((v0.w - mu) * rs * g0.w + b0.w);
  r[4] = f2bf((v1.x - mu) * rs * g1.x + b1.x);
  r[5] = f2bf((v1.y - mu) * rs * g1.y + b1.y);
  r[6] = f2bf((v1.z - mu) * rs * g1.z + b1.z);
  r[7] = f2bf((v1.w - mu) * rs * g1.w + b1.w);
  *(u16x8*)(dst + t * 8) = r;
}

// ---------------- GEMM 256x256, BK=64, 8 waves, 8-PHASE template (m201 port) ----
// LDS 128KB = [dbuf 2][A|B][256x64]. Per iter: 2 K-tiles, 8 phases, each phase
// {ds_read subtile, stage 1 half-tile (2 gloads), barrier, lgkmcnt(0), 16 MFMA,
// barrier}. Counted vmcnt(4) only at phase 3/7 boundaries (2 half-tiles stay in
// flight; never drains in steady state). Swizzle: granule ^= row&7 both sides.
// mode 10: QKV merged (576 tiles: mat=wg/192); mode 2: linear f32 (192 tiles)
__global__ __launch_bounds__(512, 2) void gemm8p_kernel(
    const unsigned short* __restrict__ Aq, const unsigned short* __restrict__ Akv,
    const unsigned short* __restrict__ Wq, const unsigned short* __restrict__ Wk,
    const unsigned short* __restrict__ Wv,
    void* __restrict__ d0, void* __restrict__ d1,
    void* __restrict__ d2, void* __restrict__ d3, int mode) {
  __shared__ unsigned short lds[2][2][16384];   // [dbuf][A=0|B=1][256*64] = 128 KB

  const int tid = threadIdx.x;
  const int wid = tid >> 6, l = tid & 63;
  const int wm = wid >> 2, wn = wid & 3;        // 2M x 4N waves; wave tile 128x64
  const int fr = l & 15, fg = l >> 4;
  const int swr = (fr & 7) << 3;                // frag k-offset XOR (shorts)

  // XCD-chunked swizzle (grid % 8 == 0)
  const int cpx = gridDim.x >> 3;
  int wg = ((int)blockIdx.x & 7) * cpx + ((int)blockIdx.x >> 3);

  const unsigned short* A = Aq;
  const unsigned short* W = Wq;
  int emode = mode;
  if (mode == 10) {
    int mat = wg / 192; wg -= mat * 192;
    if (mat == 0)      { emode = 0; }
    else if (mat == 1) { emode = 3; A = Akv; W = Wk; }
    else               { emode = 1; A = Akv; W = Wv; }
  }
  const int bm = wg >> 3, bn = wg & 7;          // N=2048 -> 8 col tiles of 256

  // staging: wave covers 16 rows/half-tile via 2 gloads (8 rows each);
  // source granule pre-swizzled by row&7 so linear DMA lands in swizzled slots.
  const int lr8 = l >> 3;                        // 0..7 (row within 8-row chunk)
  const int gcol = ((l & 7) ^ lr8) * 8;          // swizzled 8-short granule
  const unsigned short* gaB = A + (size_t)(bm * 256 + wid * 16 + lr8) * 2048 + gcol;
  const unsigned short* gbB = W + (size_t)(bn * 256 + wid * 16 + lr8) * 2048 + gcol;

#define STAGE_A(kt, h) do {                                                       \
    unsigned short* _d = &lds[(kt) & 1][0][(h) * 8192 + wid * 1024];              \
    const unsigned short* _s = gaB + (size_t)(h) * 128 * 2048 + (size_t)(kt) * 64;\
    gload_lds16(_s,            _d);                                               \
    gload_lds16(_s + 8 * 2048, _d + 512);                                         \
  } while (0)
#define STAGE_B(kt, h) do {                                                       \
    unsigned short* _d = &lds[(kt) & 1][1][(h) * 8192 + wid * 1024];              \
    const unsigned short* _s = gbB + (size_t)(h) * 128 * 2048 + (size_t)(kt) * 64;\
    gload_lds16(_s,            _d);                                               \
    gload_lds16(_s + 8 * 2048, _d + 512);                                         \
  } while (0)

#define RD_A(dst, miB, dbf)                                                       \
  _Pragma("unroll") for (int _m = 0; _m < 4; ++_m)                                \
  _Pragma("unroll") for (int _k = 0; _k < 2; ++_k)                                \
    dst[_m][_k] = *(const bf16x8*)&lds[dbf][0][(wm * 128 + ((miB) + _m) * 16 + fr) * 64 + ((_k * 32 + fg * 8) ^ swr)];
#define RD_B(dst, niB, dbf)                                                       \
  _Pragma("unroll") for (int _n = 0; _n < 2; ++_n)                                \
  _Pragma("unroll") for (int _k = 0; _k < 2; ++_k)                                \
    dst[_n][_k] = *(const bf16x8*)&lds[dbf][1][(wn * 64 + ((niB) + _n) * 16 + fr) * 64 + ((_k * 32 + fg * 8) ^ swr)];

#define MM16(aS, miB, niB) do {                                                   \
    __builtin_amdgcn_s_setprio(1);                                                \
    _Pragma("unroll") for (int _m = 0; _m < 4; ++_m)                              \
    _Pragma("unroll") for (int _n = 0; _n < 2; ++_n)                              \
    _Pragma("unroll") for (int _k = 0; _k < 2; ++_k)                              \
      acc[(miB) + _m][(niB) + _n] =                                               \
        MFMA16(aS[_m][_k], bb[_n][_k], acc[(miB) + _m][(niB) + _n]);              \
    __builtin_amdgcn_s_setprio(0);                                                \
  } while (0)

#define BAR __builtin_amdgcn_s_barrier()
#define LG0 do { asm volatile("s_waitcnt lgkmcnt(0)" ::: "memory");               \
                 __builtin_amdgcn_sched_barrier(0); } while (0)

  f32x4 acc[8][4] = {};
  bf16x8 aLo[4][2], aHi[4][2], bb[2][2];

  // prologue: K-tile 0 (A+B) + K-tile 1 (A); B(1) staged in iter 0 phases 0-1
  STAGE_A(0, 0); STAGE_A(0, 1); STAGE_B(0, 0); STAGE_B(0, 1);
  STAGE_A(1, 0); STAGE_A(1, 1);
  asm volatile("s_waitcnt vmcnt(4)" ::: "memory");   // K-tile 0 landed
  BAR;

  for (int i = 0; i < 16; ++i) {
    const int kt0 = 2 * i;
    const bool nl = (i < 15);
    // ---- phase 0: A-lo + B01 of dbuf0; stage Bh0(kt0+1) ----
    RD_A(aLo, 0, 0); RD_B(bb, 0, 0);
    STAGE_B(kt0 + 1, 0);
    BAR; LG0;
    MM16(aLo, 0, 0);
    BAR;
    // ---- phase 1: A-hi; stage Bh1(kt0+1) ----
    RD_A(aHi, 4, 0);
    STAGE_B(kt0 + 1, 1);
    BAR; LG0;
    MM16(aHi, 4, 0);
    BAR;
    // ---- phase 2: B23; stage Ah0(kt0+2) [A slot freed by phase-1 barrier] ----
    RD_B(bb, 2, 0);
    if (nl) STAGE_A(kt0 + 2, 0);
    BAR; LG0;
    MM16(aLo, 0, 2);
    BAR;
    // ---- phase 3: stage Ah1(kt0+2); boundary vmcnt ----
    if (nl) STAGE_A(kt0 + 2, 1);
    BAR; LG0;
    MM16(aHi, 4, 2);
    __builtin_amdgcn_sched_barrier(0);
    if (nl) asm volatile("s_waitcnt vmcnt(4)" ::: "memory");  // A(kt1),B(kt1) landed
    else    asm volatile("s_waitcnt vmcnt(0)" ::: "memory");
    BAR;
    // ---- phase 4: A-lo + B01 of dbuf1; stage Bh0(kt0+2) [B slot freed ph2] ----
    RD_A(aLo, 0, 1); RD_B(bb, 0, 1);
    if (nl) STAGE_B(kt0 + 2, 0);
    BAR; LG0;
    MM16(aLo, 0, 0);
    BAR;
    // ---- phase 5: A-hi; stage Bh1(kt0+2) ----
    RD_A(aHi, 4, 1);
    if (nl) STAGE_B(kt0 + 2, 1);
    BAR; LG0;
    MM16(aHi, 4, 0);
    BAR;
    // ---- phase 6: B23; stage Ah0(kt0+3) [A1 slot freed by phase-5 barrier] ----
    RD_B(bb, 2, 1);
    if (nl) STAGE_A(kt0 + 3, 0);
    BAR; LG0;
    MM16(aLo, 0, 2);
    BAR;
    // ---- phase 7: stage Ah1(kt0+3); boundary vmcnt ----
    if (nl) STAGE_A(kt0 + 3, 1);
    BAR; LG0;
    MM16(aHi, 4, 2);
    __builtin_amdgcn_sched_barrier(0);
    if (nl) asm volatile("s_waitcnt vmcnt(4)" ::: "memory");  // A(kt0+2),B(kt0+2) landed
    BAR;
  }
#undef STAGE_A
#undef STAGE_B
#undef RD_A
#undef RD_B
#undef MM16
#undef BAR
#undef LG0

  // ---- epilogue ----
#pragma unroll
  for (int mi = 0; mi < 8; ++mi) {
    const int row0 = bm * 256 + wm * 128 + mi * 16 + fg * 4;
    if (emode == 1) {
      int b = row0 / 3072, s0 = row0 - b * 3072;
#pragma unroll
      for (int ni = 0; ni < 4; ++ni) {
        int col = bn * 256 + wn * 64 + ni * 16 + fr;
        int hh = col >> 7, d = col & 127;
        size_t bh = (size_t)(b * NH + hh);
        size_t idx = (bh * 128 + d) * (size_t)3072 + ((s0 & ~31) | ((s0 & 31) ^ ((d & 3) << 3)));
        uint2 pk;
        pk.x = cvtpk(acc[mi][ni][0], acc[mi][ni][1]);
        pk.y = cvtpk(acc[mi][ni][2], acc[mi][ni][3]);
        *(uint2*)((unsigned short*)d3 + idx) = pk;
      }
    } else {
#pragma unroll
      for (int r = 0; r < 4; ++r) {
        int row = row0 + r;
#pragma unroll
        for (int ni = 0; ni < 4; ++ni) {
          int col = bn * 256 + wn * 64 + ni * 16 + fr;
          float v = acc[mi][ni][r];
          if (emode == 2) {
            ((float*)d0)[(size_t)row * 2048 + col] = v;   // d_out is FLOAT32
          } else if (emode == 0) {
            int hh = col >> 7, d = col & 127;
            if (row < 4096) {
              int b = row >> 11, s = row & 2047;
              ((unsigned short*)d0)[((size_t)(b * NH + hh) * 2048 + s) * 128 + d] = f2bf(v);
            } else {
              int rr = row - 4096, b = rr >> 10, s = rr & 1023;
              ((unsigned short*)d1)[((size_t)(b * NH + hh) * 1024 + s) * 128 + d] = f2bf(v);
            }
          } else {  // emode == 3 : K, d-swizzled
            int b = row / 3072, s = row - b * 3072;
            int hh = col >> 7, d = col & 127;
            size_t bh = (size_t)(b * NH + hh);
            ((unsigned short*)d2)[(bh * 3072 + s) * 128 + (d ^ ((s & 7) << 3))] = f2bf(v);
          }
        }
      }
    }
  }
}

// ---------------- flash attention: dbuf K/V, KVBLK=32, counted-vmcnt -------------
// grid 768 (XCD-chunked). 4 waves x 32 q. LDS: Ks[2]|Vs[2]|P = 40KB.
__global__ __launch_bounds__(256, 3) void attn_kernel(
    const unsigned short* __restrict__ Qt, const unsigned short* __restrict__ Qi,
    const unsigned short* __restrict__ Kh, const unsigned short* __restrict__ Vt,
    unsigned short* __restrict__ AOt, unsigned short* __restrict__ AOi) {
  __shared__ unsigned short Sh[20480];  // Ks0|Ks1|Vs0|Vs1|P(4x1024)

  const int lin = blockIdx.x;
  const int w768 = (lin & 7) * 96 + (lin >> 3);
  const int qt24 = w768 % 24;
  const int hb   = w768 / 24;
  const int h = hb & 15, b = hb >> 4;
  const bool is_text = qt24 < 16;
  const int qt = is_text ? qt24 : qt24 - 16;
  const int Sq = is_text ? 2048 : 1024;
  const unsigned short* Qh = is_text ? Qt : Qi;
  unsigned short* AO = is_text ? AOt : AOi;

  const int tid = threadIdx.x;
  const int w = tid >> 6, l = tid & 63;
  const int fr = l & 15, fg = l >> 4;
  const size_t bh = (size_t)(b * NH + h);
  unsigned short* Pw = Sh + 16384 + w * 1024;   // per-wave [32 q][32 k]

  const unsigned short* Qbase = Qh + (bh * Sq + (size_t)qt * 128 + w * 32) * HD;
  bf16x8 qf[2][4];
#pragma unroll
  for (int h2 = 0; h2 < 2; ++h2)
#pragma unroll
    for (int c = 0; c < 4; ++c)
      qf[h2][c] = *(const bf16x8*)(Qbase + (h2 * 16 + fr) * HD + c * 32 + fg * 8);

  f32x4 o[2][8] = {};
  float m[2]    = {-1e30f, -1e30f};
  float lsum[2] = {0.f, 0.f};

  const unsigned short* Kb = Kh + bh * (size_t)SKV * HD;
  const unsigned short* Vb = Vt + bh * (size_t)HD * SKV;

  const int swk = (fr & 7) << 3;   // K d-swizzle (within 128)
  const int swv = (fr & 3) << 3;   // V s-swizzle (within 32) + P swizzle

#define STAGE_K(kt, half) do {                                                   \
    unsigned short* _d = Sh + (half) * 4096 + w * 1024;                          \
    const unsigned short* _s = Kb + (size_t)((kt) * 32 + w * 8 + (l >> 4)) * 128 \
                               + (l & 15) * 8;                                   \
    gload_lds16(_s, _d);                                                         \
    gload_lds16(_s + 4 * 128, _d + 512);                                         \
  } while (0)
#define STAGE_V(kt, half) do {                                                   \
    unsigned short* _d = Sh + 8192 + (half) * 4096 + w * 1024;                   \
    const unsigned short* _s = Vb + (size_t)(w * 32 + (l >> 2)) * SKV            \
                               + (kt) * 32 + (l & 3) * 8;                        \
    gload_lds16(_s, _d);                                                         \
    gload_lds16(_s + 16 * SKV, _d + 512);                                        \
  } while (0)

  STAGE_K(0, 0);
  for (int kt = 0; kt < 96; ++kt) {
    const int half = kt & 1;
    STAGE_V(kt, half);
    asm volatile("s_waitcnt vmcnt(2)" ::: "memory");   // K(kt) ready; V(kt) in flight
    __builtin_amdgcn_s_barrier();

    const unsigned short* Ksc = Sh + half * 4096;
    f32x4 sT[2][2] = {};
#pragma unroll
    for (int j = 0; j < 2; ++j) {
      const int krb = (j * 16 + fr) * 128;
#pragma unroll
      for (int c = 0; c < 4; ++c) {
        bf16x8 kf = *(const bf16x8*)&Ksc[krb + ((c * 32 + fg * 8) ^ swk)];
        sT[0][j] = MFMA16(kf, qf[0][c], sT[0][j]);
        sT[1][j] = MFMA16(kf, qf[1][c], sT[1][j]);
      }
    }
    if (kt < 95) STAGE_K(kt + 1, half ^ 1);

#pragma unroll
    for (int h2 = 0; h2 < 2; ++h2) {
      float tm = fmaxf(fmaxf(fmaxf(sT[h2][0][0], sT[h2][0][1]),
                             fmaxf(sT[h2][0][2], sT[h2][0][3])),
                       fmaxf(fmaxf(sT[h2][1][0], sT[h2][1][1]),
                             fmaxf(sT[h2][1][2], sT[h2][1][3])));
      tm = fmaxf(tm, __shfl_xor(tm, 16));
      tm = fmaxf(tm, __shfl_xor(tm, 32));
      if (__any(tm - m[h2] > DEFER_THR)) {
        float mn = fmaxf(m[h2], tm);
        float al = exp2hw(m[h2] - mn);
#pragma unroll
        for (int nt = 0; nt < 8; ++nt) {
          f32x4 t = o[h2][nt];
          t[0] *= al; t[1] *= al; t[2] *= al; t[3] *= al;
          o[h2][nt] = t;
        }
        lsum[h2] *= al;
        m[h2] = mn;
      }
      const float mm = m[h2];
      float p00 = exp2hw(sT[h2][0][0] - mm), p01 = exp2hw(sT[h2][0][1] - mm);
      float p02 = exp2hw(sT[h2][0][2] - mm), p03 = exp2hw(sT[h2][0][3] - mm);
      float p10 = exp2hw(sT[h2][1][0] - mm), p11 = exp2hw(sT[h2][1][1] - mm);
      float p12 = exp2hw(sT[h2][1][2] - mm), p13 = exp2hw(sT[h2][1][3] - mm);
      lsum[h2] += (p00 + p01 + p02 + p03) + (p10 + p11 + p12 + p13);
      unsigned short* prow = &Pw[(h2 * 16 + fr) * 32];
      uint2 w0; w0.x = cvtpk(p00, p01); w0.y = cvtpk(p02, p03);
      uint2 w1; w1.x = cvtpk(p10, p11); w1.y = cvtpk(p12, p13);
      *(uint2*)(prow + ((fg * 4) ^ swv))      = w0;
      *(uint2*)(prow + ((16 + fg * 4) ^ swv)) = w1;
    }

    if (kt < 95) asm volatile("s_waitcnt vmcnt(2)" ::: "memory");  // V(kt) ready
    else         asm volatile("s_waitcnt vmcnt(0)" ::: "memory");
    __builtin_amdgcn_s_barrier();

    asm volatile("s_waitcnt lgkmcnt(0)" ::: "memory");
    __builtin_amdgcn_sched_barrier(0);

    const unsigned short* Vsc = Sh + 8192 + half * 4096;
    bf16x8 pb[2];
#pragma unroll
    for (int h2 = 0; h2 < 2; ++h2)
      pb[h2] = *(const bf16x8*)&Pw[(h2 * 16 + fr) * 32 + ((fg * 8) ^ swv)];
#pragma unroll
    for (int nt = 0; nt < 8; ++nt) {
      bf16x8 vf = *(const bf16x8*)&Vsc[(nt * 16 + fr) * 32 + ((fg * 8) ^ swv)];
      o[0][nt] = MFMA16(vf, pb[0], o[0][nt]);
      o[1][nt] = MFMA16(vf, pb[1], o[1][nt]);
    }
    __builtin_amdgcn_s_barrier();
  }
#undef STAGE_K
#undef STAGE_V

  float inv[2];
#pragma unroll
  for (int h2 = 0; h2 < 2; ++h2) {
    float t = lsum[h2];
    t += __shfl_xor(t, 16);
    t += __shfl_xor(t, 32);
    inv[h2] = 1.0f / t;
  }
  unsigned short* Os = &Sh[w * 4096];
#pragma unroll
  for (int h2 = 0; h2 < 2; ++h2) {
    unsigned short* orow = &Os[(h2 * 16 + fr) * 128];
    const int sw8 = (fr & 7) << 3;
#pragma unroll
    for (int nt = 0; nt < 8; ++nt) {
      uint2 pk;
      pk.x = cvtpk(o[h2][nt][0] * inv[h2], o[h2][nt][1] * inv[h2]);
      pk.y = cvtpk(o[h2][nt][2] * inv[h2], o[h2][nt][3] * inv[h2]);
      *(uint2*)(orow + ((nt * 16 + fg * 4) ^ sw8)) = pk;
    }
  }
  asm volatile("s_waitcnt lgkmcnt(0)" ::: "memory");
  __builtin_amdgcn_sched_barrier(0);
  const int qr4 = l >> 4;
  const int dc = (l & 15) * 8;
  unsigned short* AObase = AO + ((size_t)b * Sq + (size_t)qt * 128 + w * 32) * D_MODEL + h * HD;
#pragma unroll
  for (int g = 0; g < 8; ++g) {
    const int row = g * 4 + qr4;
    bf16x8 v = *reinterpret_cast<const bf16x8*>(&Os[row * 128 + (dc ^ ((row & 7) << 3))]);
    *reinterpret_cast<bf16x8*>(&AObase[(size_t)row * D_MODEL + dc]) = v;
  }
}

// ---------------- host launch ----------------
extern "C" void kernel_launch(void* const* d_in, const int* in_sizes, int n_in,
                              void* d_out, int out_size, void* d_ws, size_t ws_size,
                              hipStream_t stream) {
  const float* q_text  = (const float*)d_in[0];
  const float* q_image = (const float*)d_in[1];
  const float* k_text  = (const float*)d_in[2];
  const float* k_image = (const float*)d_in[3];
  const float* Wq = (const float*)d_in[4];
  const float* Wk = (const float*)d_in[5];
  const float* Wv = (const float*)d_in[6];
  const float* Wo = (const float*)d_in[7];
  const float* ln_tg = (const float*)d_in[8];
  const float* ln_tb = (const float*)d_in[9];
  const float* ln_ig = (const float*)d_in[10];
  const float* ln_ib = (const float*)d_in[11];

  // workspace layout (bf16 elements)
  unsigned short* wq  = (unsigned short*)d_ws;
  unsigned short* wk  = wq  + 4194304;
  unsigned short* wv  = wk  + 4194304;
  unsigned short* wo  = wv  + 4194304;
  unsigned short* xqt = wo  + 4194304;   // LN'd q_text  [4096,2048]; later AO_text
  unsigned short* xqi = xqt + 8388608;   // LN'd q_image [2048,2048]; later AO_image
  unsigned short* xk  = xqi + 4194304;   // LN'd concat k [2,3072,2048]
  unsigned short* qht = xk  + 12582912;  // [2,16,2048,128]
  unsigned short* qhi = qht + 8388608;   // [2,16,1024,128]
  unsigned short* kh  = qhi + 4194304;   // [2,16,3072,128] (d-swizzled)
  unsigned short* vt  = kh  + 12582912;  // [2,16,128,3072] (s-swizzled, 32-groups)
  const size_t needed = (size_t)(vt + 12582912 - wq) * 2;
  if (ws_size < needed) return;

  cvt_w_kernel<<<dim3(2048, 4), 256, 0, stream>>>(Wq, Wk, Wv, Wo, wq);

  // all LayerNorms in ONE dispatch (12288 rows)
  ln_all_kernel<<<12288, 256, 0, stream>>>(q_text, q_image, k_text, k_image,
                                           ln_tg, ln_tb, ln_ig, ln_ib,
                                           xqt, xqi, xk);

  // Q+K+V in ONE dispatch: 576 tiles of 256^2, 8-phase pipeline
  gemm8p_kernel<<<576, 512, 0, stream>>>(xqt, xk, wq, wk, wv, qht, qhi, kh, vt, 10);

  attn_kernel<<<768, 256, 0, stream>>>(qht, qhi, kh, vt, xqt, xqi);

  // out projection: 192 tiles, f32 straight into d_out
  gemm8p_kernel<<<192, 512, 0, stream>>>(xqt, nullptr, wo, nullptr, nullptr,
                                         d_out, nullptr, nullptr, nullptr, 2);
}